// Round 7
// baseline (742.478 us; speedup 1.0000x reference)
//
#include <hip/hip_runtime.h>
#include <hip/hip_bf16.h>
#include <math.h>

#define BB 16
#define HH 56
#define WW 56
#define CC0 192
#define NHH 6
#define HDD 32
#define NPOS (HH*WW)       // 3136
#define MROWS (BB*NPOS)    // 50176
#define C4 (4*CC0)         // 768

typedef __hip_bfloat16 bf16;
typedef short short8 __attribute__((ext_vector_type(8)));
typedef short short4v __attribute__((ext_vector_type(4)));
typedef float f32x4 __attribute__((ext_vector_type(4)));

__device__ __forceinline__ float b2f(bf16 v){ return __bfloat162float(v); }
__device__ __forceinline__ bf16 f2b(float v){ return __float2bfloat16(v); }
__device__ __forceinline__ short f2s(float v){ bf16 b = __float2bfloat16(v); return *(short*)&b; }
__device__ __forceinline__ float s2f(short s){ bf16 b; *(short*)&b = s; return __bfloat162float(b); }
__device__ __forceinline__ float fast_gelu(float x){
  float u = 1.5957691216f * (x + 0.044715f*x*x*x);
  float t = 1.f - 2.f/(__expf(u) + 1.f);
  return 0.5f*x*(1.f + t);
}
// XCD-aware swizzle: same-XCD blocks (bid%8 const under round-robin dispatch)
// get contiguous spatial chunks -> conv neighborhood reuse stays in per-XCD L2.
__device__ __forceinline__ int swz8(int bid, int nblk){
  return (bid & 7) * (nblk >> 3) + (bid >> 3);
}

// ---------------- weight pre-convert: f32 [K][N] -> bf16 W^T [N][K] ----------------
__global__ __launch_bounds__(256) void convert_weights(
    const float* __restrict__ w0, const float* __restrict__ w1,
    const float* __restrict__ w2, const float* __restrict__ w3,
    const float* __restrict__ w4, const float* __restrict__ w5,
    short* __restrict__ dst){
  int t = blockIdx.x*256 + threadIdx.x;
  int e = t*4;
  if (e >= 479232) return;
  const float* src; int K, N, off;
  if      (e <  36864){ src=w0; K=192; N=192; off=0; }
  else if (e <  73728){ src=w1; K=192; N=192; off=36864; }
  else if (e < 147456){ src=w2; K=192; N=384; off=73728; }
  else if (e < 184320){ src=w3; K=192; N=192; off=147456; }
  else if (e < 331776){ src=w4; K=192; N=768; off=184320; }
  else                { src=w5; K=768; N=192; off=331776; }
  int le = e - off;
  int n = le / K, k = le % K;
  short4v o;
  #pragma unroll
  for (int l = 0; l < 4; ++l) o[l] = f2s(src[(size_t)(k+l)*N + n]);
  *(short4v*)(dst + e) = o;
}

// ---------------- vectorized depthwise 3x3 conv (XCD-swizzled) ----------------
// MODE 0: out(f32) = in(f32) + conv+bias     (cpe1/cpe2)
// MODE 1: out(bf16) = silu(conv+bias)        (dwc, in bf16)
// MODE 2: out(bf16) += conv+bias             (lepe, in bf16, bf16 RMW)
template<typename TIN, int CC, int MODE>
__global__ __launch_bounds__(256) void dwconv_v(const TIN* __restrict__ in,
    const float* __restrict__ w, const float* __restrict__ bias, void* __restrict__ out){
  constexpr int VEC = 16 / (int)sizeof(TIN);
  constexpr int NG = CC / VEC;
  int idx = swz8(blockIdx.x, gridDim.x)*256 + threadIdx.x;
  int cg = idx % NG; int pos = idx / NG;
  int b = pos / NPOS; int ij = pos % NPOS; int i = ij / WW; int j = ij % WW;
  int cb = cg * VEC;
  float acc[VEC];
  #pragma unroll
  for (int l = 0; l < VEC; ++l) acc[l] = bias[cb + l];
  #pragma unroll
  for (int di = 0; di < 3; ++di){
    int ii = i + di - 1;
    if (ii < 0 || ii >= HH) continue;
    #pragma unroll
    for (int dj = 0; dj < 3; ++dj){
      int jj = j + dj - 1;
      if (jj < 0 || jj >= WW) continue;
      size_t off = ((size_t)b*NPOS + ii*WW + jj)*CC + cb;
      const float* wp = w + (di*3 + dj)*CC + cb;
      if constexpr (sizeof(TIN) == 2){
        short8 v = *(const short8*)((const short*)in + off);
        #pragma unroll
        for (int l = 0; l < 8; ++l) acc[l] += s2f(v[l]) * wp[l];
      } else {
        f32x4 v = *(const f32x4*)((const float*)in + off);
        #pragma unroll
        for (int l = 0; l < 4; ++l) acc[l] += v[l] * wp[l];
      }
    }
  }
  size_t oidx = (size_t)pos*CC + cb;
  if constexpr (MODE == 0){
    f32x4 r = *(const f32x4*)((const float*)in + oidx);
    f32x4 o;
    #pragma unroll
    for (int l = 0; l < 4; ++l) o[l] = r[l] + acc[l];
    *(f32x4*)((float*)out + oidx) = o;
  } else if constexpr (MODE == 1){
    short8 o;
    #pragma unroll
    for (int l = 0; l < 8; ++l){ float s = acc[l]/(1.f + expf(-acc[l])); o[l] = f2s(s); }
    *(short8*)((short*)out + oidx) = o;
  } else {
    short* op = (short*)out + oidx;
    short8 r = *(short8*)op;
    short8 o;
    #pragma unroll
    for (int l = 0; l < 8; ++l) o[l] = f2s(s2f(r[l]) + acc[l]);
    *(short8*)op = o;
  }
}

// ---------------- LayerNorm over C=192 (f32 in, bf16 out) ----------------
__global__ __launch_bounds__(64) void ln192_kernel(const float* __restrict__ x,
    const float* __restrict__ g, const float* __restrict__ bb, bf16* __restrict__ out){
  int row = blockIdx.x; int t = threadIdx.x;
  const float* xr = x + (size_t)row*CC0;
  float v0 = xr[t], v1 = xr[t+64], v2 = xr[t+128];
  float s = v0+v1+v2;
  float q = v0*v0+v1*v1+v2*v2;
  #pragma unroll
  for (int m = 1; m < 64; m <<= 1){ s += __shfl_xor(s, m, 64); q += __shfl_xor(q, m, 64); }
  float mean = s * (1.f/CC0);
  float rstd = rsqrtf(q * (1.f/CC0) - mean*mean + 1e-5f);
  bf16* orow = out + (size_t)row*CC0;
  orow[t]     = f2b((v0-mean)*rstd*g[t]     + bb[t]);
  orow[t+64]  = f2b((v1-mean)*rstd*g[t+64]  + bb[t+64]);
  orow[t+128] = f2b((v2-mean)*rstd*g[t+128] + bb[t+128]);
}

// ---------------- MFMA GEMM: A [M,K] bf16-ish @ W^T [N,K] bf16 + bias ----------------
// ALOAD: 0 = bf16 direct, 1 = bf16 * bf16 product
// EPI: 0 = bf16, 1 = silu->bf16, 2 = elu+1 split ->bf16, 3 = +addf(f32) ->f32
#define BM 256
#define BN 64
#define BK 32
#define LDA 40
template<int K, int N, int ALOAD, int EPI>
__global__ __launch_bounds__(256) void mfma_gemm(
    const void* __restrict__ a0v, const void* __restrict__ a1v,
    const short* __restrict__ wT, const float* __restrict__ bias,
    const float* __restrict__ addf, void* __restrict__ out0, void* __restrict__ out1){
  __shared__ short As[BM*LDA];
  __shared__ short Bs[BN*LDA];
  int tid = threadIdx.x;
  int wave = tid >> 6, lane = tid & 63;
  size_t m0 = (size_t)blockIdx.x * BM;
  int n0 = blockIdx.y * BN;
  int wm = wave * 64;
  int am = lane & 15, ak = (lane >> 4) * 8;

  f32x4 acc[4][4];
  #pragma unroll
  for (int mt = 0; mt < 4; ++mt)
    #pragma unroll
    for (int nt = 0; nt < 4; ++nt)
      acc[mt][nt] = (f32x4){0.f,0.f,0.f,0.f};

  for (int k0 = 0; k0 < K; k0 += BK){
    if constexpr (ALOAD == 0){
      const short* A = (const short*)a0v;
      #pragma unroll
      for (int it = 0; it < 4; ++it){
        int idx = it*256 + tid;
        int row = idx >> 2; int ko = (idx & 3) * 8;
        short8 v = *(const short8*)(A + (m0 + row)*(size_t)K + k0 + ko);
        *(short8*)&As[row*LDA + ko] = v;
      }
    } else {
      const short* A0p = (const short*)a0v;
      const short* A1p = (const short*)a1v;
      #pragma unroll
      for (int it = 0; it < 4; ++it){
        int idx = it*256 + tid;
        int row = idx >> 2; int ko = (idx & 3) * 8;
        size_t off = (m0 + row)*(size_t)K + k0 + ko;
        short8 va = *(const short8*)(A0p + off);
        short8 vb = *(const short8*)(A1p + off);
        short8 o;
        #pragma unroll
        for (int l = 0; l < 8; ++l) o[l] = f2s(s2f(va[l]) * s2f(vb[l]));
        *(short8*)&As[row*LDA + ko] = o;
      }
    }
    {
      int row = tid >> 2; int ko = (tid & 3) * 8;
      short8 v = *(const short8*)(wT + (size_t)(n0 + row)*K + k0 + ko);
      *(short8*)&Bs[row*LDA + ko] = v;
    }
    __syncthreads();
    short8 af[4], bfr[4];
    #pragma unroll
    for (int mt = 0; mt < 4; ++mt) af[mt] = *(short8*)&As[(wm + mt*16 + am)*LDA + ak];
    #pragma unroll
    for (int nt = 0; nt < 4; ++nt) bfr[nt] = *(short8*)&Bs[(nt*16 + am)*LDA + ak];
    #pragma unroll
    for (int mt = 0; mt < 4; ++mt)
      #pragma unroll
      for (int nt = 0; nt < 4; ++nt)
        acc[mt][nt] = __builtin_amdgcn_mfma_f32_16x16x32_bf16(af[mt], bfr[nt], acc[mt][nt], 0, 0, 0);
    __syncthreads();
  }

  int cn = lane & 15;
  int cr = (lane >> 4) * 4;
  #pragma unroll
  for (int mt = 0; mt < 4; ++mt){
    #pragma unroll
    for (int nt = 0; nt < 4; ++nt){
      int gn = n0 + nt*16 + cn;
      float bv = bias[gn];
      #pragma unroll
      for (int r = 0; r < 4; ++r){
        size_t gm = m0 + wm + mt*16 + cr + r;
        float v = acc[mt][nt][r] + bv;
        if constexpr (EPI == 0){
          ((bf16*)out0)[gm*N + gn] = f2b(v);
        } else if constexpr (EPI == 1){
          ((bf16*)out0)[gm*N + gn] = f2b(v / (1.f + expf(-v)));
        } else if constexpr (EPI == 2){
          float rv = (v > 0.f) ? (v + 1.f) : expf(v);
          if (n0 < CC0) ((bf16*)out0)[gm*CC0 + gn] = f2b(rv);
          else          ((bf16*)out1)[gm*CC0 + (gn - CC0)] = f2b(rv);
        } else {
          ((float*)out0)[gm*N + gn] = addf[gm*N + gn] + v;
        }
      }
    }
  }
}

// ---------------- RoPE tables (H,W,96) ----------------
__global__ void rope_tables_kernel(float* __restrict__ cosT, float* __restrict__ sinT){
  int idx = blockIdx.x*256 + threadIdx.x;
  if (idx >= NPOS*96) return;
  int t = idx % 96; int ij = idx / 96; int i = ij / WW; int j = ij % WW;
  int kk = (t < 48) ? t : (t - 48);
  float th = expf(-(float)kk * 0.19188209108283716f);
  float pos = (t < 48) ? (float)i : (float)j;
  float ang = pos * th;
  cosT[idx] = cosf(ang);
  sinT[idx] = sinf(ang);
}

// ---------------- kmean (k in bf16) ----------------
__global__ __launch_bounds__(CC0) void kmean_kernel(const bf16* __restrict__ k, float* __restrict__ kmean){
  int b = blockIdx.x / 7; int chunk = blockIdx.x % 7; int c = threadIdx.x;
  const bf16* kp = k + ((size_t)b*NPOS + (size_t)chunk*448)*CC0 + c;
  float s = 0.f;
  for (int r = 0; r < 448; ++r) s += b2f(kp[(size_t)r*CC0]);
  atomicAdd(&kmean[b*CC0 + c], s * (1.f/NPOS));
}

// ---------------- kv (k, h in bf16), 56 N-chunks for occupancy ----------------
#define KVCH 56
__global__ __launch_bounds__(256) void kv_kernel(const bf16* __restrict__ kbuf,
    const bf16* __restrict__ hbuf, const float* __restrict__ cosT,
    const float* __restrict__ sinT, float* __restrict__ kv){
  int bi = blockIdx.x;
  int chunk = bi % KVCH; bi /= KVCH;
  int h = bi % NHH; int b = bi / NHH;
  int tid = threadIdx.x;
  int r8 = tid >> 5, lane = tid & 31;
  __shared__ float krs[8][32];
  __shared__ float vvs[8][32];
  int d = tid >> 3; int ebase = (tid & 7) * 4;
  float a0 = 0.f, a1 = 0.f, a2 = 0.f, a3 = 0.f;
  int c = h*HDD + lane;
  int t = c >> 1;
  bool odd = (lane & 1);
  for (int step = 0; step < NPOS/(KVCH*8); ++step){
    int n = chunk*(NPOS/KVCH) + step*8 + r8;
    size_t row = (size_t)b*NPOS + n;
    float kc = b2f(kbuf[row*CC0 + c]);
    float kp = b2f(kbuf[row*CC0 + (c ^ 1)]);
    float cs = cosT[(size_t)n*96 + t], sn = sinT[(size_t)n*96 + t];
    krs[r8][lane] = odd ? (cs*kc + sn*kp) : (cs*kc - sn*kp);
    vvs[r8][lane] = b2f(hbuf[row*CC0 + c]);
    __syncthreads();
    #pragma unroll
    for (int nn = 0; nn < 8; ++nn){
      float kk2 = krs[nn][d];
      a0 += kk2 * vvs[nn][ebase+0];
      a1 += kk2 * vvs[nn][ebase+1];
      a2 += kk2 * vvs[nn][ebase+2];
      a3 += kk2 * vvs[nn][ebase+3];
    }
    __syncthreads();
  }
  const float invN = 1.f/NPOS;
  float* kvp = kv + (((size_t)(b*NHH + h)*HDD + d)*HDD) + ebase;
  atomicAdd(kvp+0, a0*invN);
  atomicAdd(kvp+1, a1*invN);
  atomicAdd(kvp+2, a2*invN);
  atomicAdd(kvp+3, a3*invN);
}

// ---------------- fused attention (q bf16 in, attn bf16 out) ----------------
__global__ __launch_bounds__(CC0) void attn_kernel(const bf16* __restrict__ q,
    const float* __restrict__ kmean, const float* __restrict__ kv,
    const float* __restrict__ cosT, const float* __restrict__ sinT,
    bf16* __restrict__ out){
  int row = blockIdx.x;
  int tid = threadIdx.x;
  int b = row / NPOS; int n = row % NPOS;
  __shared__ float qs[CC0];
  __shared__ float qrs[NHH*33];
  __shared__ float zsh[NHH];
  qs[tid] = b2f(q[(size_t)row*CC0 + tid]);
  __syncthreads();
  float pm = qs[tid] * kmean[b*CC0 + tid];
  #pragma unroll
  for (int m = 16; m >= 1; m >>= 1) pm += __shfl_xor(pm, m, 32);
  if ((tid & 31) == 0) zsh[tid >> 5] = 1.f/(pm + 1e-6f);
  int t = tid >> 1;
  float cs = cosT[(size_t)n*96 + t], sn = sinT[(size_t)n*96 + t];
  float qr = (tid & 1) ? (cs*qs[tid] + sn*qs[tid-1]) : (cs*qs[tid] - sn*qs[tid+1]);
  int hh = tid >> 5, d = tid & 31;
  qrs[hh*33 + d] = qr;
  __syncthreads();
  const float* kvp = kv + (size_t)(b*NHH + hh)*HDD*HDD;
  float acc = 0.f;
  #pragma unroll
  for (int d2 = 0; d2 < HDD; ++d2) acc += qrs[hh*33 + d2] * kvp[d2*HDD + d];
  out[(size_t)row*CC0 + tid] = f2b(acc * zsh[hh]);
}

// ---------------- fused mdw dwconv + n1/n2/n3 LN chain + gelu (XCD-swizzled) ----------------
__global__ __launch_bounds__(256) void mdw_ln_kernel(const bf16* __restrict__ f1,
    const float* __restrict__ w, const float* __restrict__ bias,
    const float* __restrict__ g1, const float* __restrict__ b1,
    const float* __restrict__ g2, const float* __restrict__ b2,
    const float* __restrict__ g3, const float* __restrict__ b3,
    bf16* __restrict__ out){
  int wv = threadIdx.x >> 6, lane = threadIdx.x & 63;
  int pos = swz8(blockIdx.x, gridDim.x)*4 + wv;
  int b = pos / NPOS; int ij = pos % NPOS; int i = ij / WW; int j = ij % WW;
  size_t rowbase = (size_t)pos * C4;
  int c0 = lane * 8;
  int c1 = 512 + lane * 4;

  float v[12], f[12];
  {
    f32x4 bv0 = *(const f32x4*)(bias + c0);
    f32x4 bv1 = *(const f32x4*)(bias + c0 + 4);
    f32x4 bv2 = *(const f32x4*)(bias + c1);
    #pragma unroll
    for (int l = 0; l < 4; ++l){ v[l] = bv0[l]; v[4+l] = bv1[l]; v[8+l] = bv2[l]; }
  }
  #pragma unroll
  for (int di = 0; di < 3; ++di){
    int ii = i + di - 1;
    if (ii < 0 || ii >= HH) continue;
    #pragma unroll
    for (int dj = 0; dj < 3; ++dj){
      int jj = j + dj - 1;
      if (jj < 0 || jj >= WW) continue;
      size_t off = ((size_t)b*NPOS + ii*WW + jj)*C4;
      const float* wp = w + (di*3 + dj)*C4;
      short8 x0 = *(const short8*)((const short*)f1 + off + c0);
      short4v x1 = *(const short4v*)((const short*)f1 + off + c1);
      f32x4 w0 = *(const f32x4*)(wp + c0);
      f32x4 w1 = *(const f32x4*)(wp + c0 + 4);
      f32x4 w2 = *(const f32x4*)(wp + c1);
      #pragma unroll
      for (int l = 0; l < 4; ++l){
        v[l]   += s2f(x0[l])   * w0[l];
        v[4+l] += s2f(x0[4+l]) * w1[l];
        v[8+l] += s2f(x1[l])   * w2[l];
      }
    }
  }
  {
    short8 x0 = *(const short8*)((const short*)f1 + rowbase + c0);
    short4v x1 = *(const short4v*)((const short*)f1 + rowbase + c1);
    #pragma unroll
    for (int l = 0; l < 8; ++l){ f[l] = s2f(x0[l]); v[l] += f[l]; }
    #pragma unroll
    for (int l = 0; l < 4; ++l){ f[8+l] = s2f(x1[l]); v[8+l] += f[8+l]; }
  }
  const float* gs[3] = {g1, g2, g3};
  const float* bs[3] = {b1, b2, b3};
  #pragma unroll
  for (int pass = 0; pass < 3; ++pass){
    float s = 0.f, q = 0.f;
    #pragma unroll
    for (int l = 0; l < 12; ++l){ s += v[l]; q += v[l]*v[l]; }
    #pragma unroll
    for (int m = 1; m < 64; m <<= 1){ s += __shfl_xor(s, m, 64); q += __shfl_xor(q, m, 64); }
    float mean = s * (1.f/C4);
    float rstd = rsqrtf(q * (1.f/C4) - mean*mean + 1e-5f);
    f32x4 g0 = *(const f32x4*)(gs[pass] + c0);
    f32x4 g1v = *(const f32x4*)(gs[pass] + c0 + 4);
    f32x4 g2v = *(const f32x4*)(gs[pass] + c1);
    f32x4 bb0 = *(const f32x4*)(bs[pass] + c0);
    f32x4 bb1 = *(const f32x4*)(bs[pass] + c0 + 4);
    f32x4 bb2 = *(const f32x4*)(bs[pass] + c1);
    #pragma unroll
    for (int l = 0; l < 4; ++l){
      v[l]   = (v[l]  -mean)*rstd*g0[l]  + bb0[l];
      v[4+l] = (v[4+l]-mean)*rstd*g1v[l] + bb1[l];
      v[8+l] = (v[8+l]-mean)*rstd*g2v[l] + bb2[l];
    }
    if (pass < 2){
      #pragma unroll
      for (int l = 0; l < 12; ++l) v[l] += f[l];
    }
  }
  short8 o0; short4v o1;
  #pragma unroll
  for (int l = 0; l < 8; ++l) o0[l] = f2s(fast_gelu(v[l]));
  #pragma unroll
  for (int l = 0; l < 4; ++l) o1[l] = f2s(fast_gelu(v[8+l]));
  *(short8*)((short*)out + rowbase + c0) = o0;
  *(short4v*)((short*)out + rowbase + c1) = o1;
}

extern "C" void kernel_launch(void* const* d_in, const int* in_sizes, int n_in,
                              void* d_out, int out_size, void* d_ws, size_t ws_size,
                              hipStream_t stream){
  (void)in_sizes; (void)n_in; (void)out_size; (void)ws_size;
  const float* X      = (const float*)d_in[0];
  const float* cpe1_w = (const float*)d_in[1];
  const float* cpe1_b = (const float*)d_in[2];
  const float* n1g    = (const float*)d_in[3];
  const float* n1b    = (const float*)d_in[4];
  const float* in_w   = (const float*)d_in[5];
  const float* in_b   = (const float*)d_in[6];
  const float* actp_w = (const float*)d_in[7];
  const float* actp_b = (const float*)d_in[8];
  const float* dwc_w  = (const float*)d_in[9];
  const float* dwc_b  = (const float*)d_in[10];
  const float* qk_w   = (const float*)d_in[11];
  const float* qk_b   = (const float*)d_in[12];
  const float* lepe_w = (const float*)d_in[13];
  const float* lepe_b = (const float*)d_in[14];
  const float* outp_w = (const float*)d_in[15];
  const float* outp_b = (const float*)d_in[16];
  const float* cpe2_w = (const float*)d_in[17];
  const float* cpe2_b = (const float*)d_in[18];
  const float* n2g    = (const float*)d_in[19];
  const float* n2b    = (const float*)d_in[20];
  const float* fc1_w  = (const float*)d_in[21];
  const float* fc1_b  = (const float*)d_in[22];
  const float* mdw_w  = (const float*)d_in[23];
  const float* mdw_b  = (const float*)d_in[24];
  const float* fc2_w  = (const float*)d_in[25];
  const float* fc2_b  = (const float*)d_in[26];
  const float* mn1g   = (const float*)d_in[27];
  const float* mn1b   = (const float*)d_in[28];
  const float* mn2g   = (const float*)d_in[29];
  const float* mn2b   = (const float*)d_in[30];
  const float* mn3g   = (const float*)d_in[31];
  const float* mn3b   = (const float*)d_in[32];

  char* ws = (char*)d_ws;
  const size_t SZF = (size_t)MROWS*CC0*4;
  const size_t SZB = (size_t)MROWS*CC0*2;
  float* A0 = (float*)(ws);                 // x1 -> x3 (f32 residual spine)
  char* base2 = ws + SZF;
  bf16* BQ = (bf16*)(base2 + 0*SZB);        // q
  bf16* BKb= (bf16*)(base2 + 1*SZB);        // k
  bf16* BA = (bf16*)(base2 + 2*SZB);        // attn (+lepe)
  bf16* B1 = (bf16*)(base2 + 3*SZB);        // act_res
  bf16* B0 = (bf16*)(base2 + 4*SZB);        // xn -> xm
  bf16* B2 = (bf16*)(base2 + 5*SZB);        // t
  bf16* B3 = (bf16*)(base2 + 6*SZB);        // h
  float* A1 = (float*)(base2);              // x2 (f32) overlays BQ+BK
  bf16*  F1 = (bf16*)(base2);               // f1 overlays slots 0-3
  bf16*  DW = (bf16*)(base2 + 4*SZB);       // gelu(n3) overlays slots 4-7
  short* WT = (short*)(base2 + 8*SZB);
  char* tail = (char*)(WT + 479232 + 64);
  float* KMEAN = (float*)tail;                 tail += (size_t)BB*CC0*4;
  float* KV    = (float*)tail;                 tail += (size_t)BB*NHH*HDD*HDD*4;
  float* COS   = (float*)tail;                 tail += (size_t)NPOS*96*4;
  float* SIN   = (float*)tail;

  const short* actpT = WT + 0;
  const short* inT   = WT + 36864;
  const short* qkT   = WT + 73728;
  const short* outpT = WT + 147456;
  const short* fc1T  = WT + 184320;
  const short* fc2T  = WT + 331776;

  const int G192F = (MROWS*(CC0/4))/256;   // 9408  (8 | G)
  const int G192B = (MROWS*(CC0/8))/256;   // 4704  (8 | G)

  convert_weights<<<(479232/4 + 255)/256, 256, 0, stream>>>(actp_w, in_w, qk_w, outp_w, fc1_w, fc2_w, WT);
  rope_tables_kernel<<<(NPOS*96 + 255)/256, 256, 0, stream>>>(COS, SIN);
  // 1. x1 = x + cpe1(x)
  dwconv_v<float,CC0,0><<<G192F, 256, 0, stream>>>(X, cpe1_w, cpe1_b, A0);
  // 2. xn = LN(x1)
  ln192_kernel<<<MROWS, 64, 0, stream>>>(A0, n1g, n1b, B0);
  // 3. act_res = silu(xn@actp)
  mfma_gemm<CC0,CC0,0,1><<<dim3(MROWS/BM,CC0/BN), 256, 0, stream>>>(B0, nullptr, actpT, actp_b, nullptr, B1, nullptr);
  // 4. t = xn@in_w + b
  mfma_gemm<CC0,CC0,0,0><<<dim3(MROWS/BM,CC0/BN), 256, 0, stream>>>(B0, nullptr, inT, in_b, nullptr, B2, nullptr);
  // 5. h = silu(dwc(t))
  dwconv_v<bf16,CC0,1><<<G192B, 256, 0, stream>>>(B2, dwc_w, dwc_b, B3);
  // 6. qk = h@qk_w; q->BQ, k->BK (bf16, elu+1)
  mfma_gemm<CC0,2*CC0,0,2><<<dim3(MROWS/BM,2*CC0/BN), 256, 0, stream>>>(B3, nullptr, qkT, qk_b, nullptr, BQ, BKb);
  // 7. kmean, kv
  hipMemsetAsync(KMEAN, 0, (size_t)BB*CC0*4, stream);
  hipMemsetAsync(KV, 0, (size_t)BB*NHH*HDD*HDD*4, stream);
  kmean_kernel<<<BB*7, CC0, 0, stream>>>(BKb, KMEAN);
  kv_kernel<<<BB*NHH*KVCH, 256, 0, stream>>>(BKb, B3, COS, SIN, KV);
  // 8. attn core -> BA
  attn_kernel<<<MROWS, CC0, 0, stream>>>(BQ, KMEAN, KV, COS, SIN, BA);
  // 9. attn += lepe(h)
  dwconv_v<bf16,CC0,2><<<G192B, 256, 0, stream>>>(B3, lepe_w, lepe_b, BA);
  // 10. x2 = x1 + (attn*act_res)@outp + b -> A1
  mfma_gemm<CC0,CC0,1,3><<<dim3(MROWS/BM,CC0/BN), 256, 0, stream>>>(BA, B1, outpT, outp_b, A0, A1, nullptr);
  // 11. x3 = x2 + cpe2(x2) -> A0
  dwconv_v<float,CC0,0><<<G192F, 256, 0, stream>>>(A1, cpe2_w, cpe2_b, A0);
  // 12. xm = LN(x3) -> B0
  ln192_kernel<<<MROWS, 64, 0, stream>>>(A0, n2g, n2b, B0);
  // 13. f1 = xm@fc1 + b -> F1
  mfma_gemm<CC0,C4,0,0><<<dim3(MROWS/BM,C4/BN), 256, 0, stream>>>(B0, nullptr, fc1T, fc1_b, nullptr, F1, nullptr);
  // 14. fused: mdw conv + n1..n3 LN chain + gelu -> DW
  mdw_ln_kernel<<<MROWS/4, 256, 0, stream>>>(F1, mdw_w, mdw_b, mn1g, mn1b, mn2g, mn2b, mn3g, mn3b, DW);
  // 15. out = x3 + gelu(n3)@fc2 + b (f32)
  mfma_gemm<C4,CC0,0,3><<<dim3(MROWS/BM,CC0/BN), 256, 0, stream>>>(DW, nullptr, fc2T, fc2_b, A0, d_out, nullptr);
}

// Round 8
// 703.964 us; speedup vs baseline: 1.0547x; 1.0547x over previous
//
#include <hip/hip_runtime.h>
#include <hip/hip_bf16.h>
#include <math.h>

#define BB 16
#define HH 56
#define WW 56
#define CC0 192
#define NHH 6
#define HDD 32
#define NPOS (HH*WW)       // 3136
#define MROWS (BB*NPOS)    // 50176
#define C4 (4*CC0)         // 768

typedef __hip_bfloat16 bf16;
typedef short short8 __attribute__((ext_vector_type(8)));
typedef short short4v __attribute__((ext_vector_type(4)));
typedef float f32x4 __attribute__((ext_vector_type(4)));

__device__ __forceinline__ float b2f(bf16 v){ return __bfloat162float(v); }
__device__ __forceinline__ bf16 f2b(float v){ return __float2bfloat16(v); }
__device__ __forceinline__ short f2s(float v){ bf16 b = __float2bfloat16(v); return *(short*)&b; }
__device__ __forceinline__ float s2f(short s){ bf16 b; *(short*)&b = s; return __bfloat162float(b); }
__device__ __forceinline__ float fast_gelu(float x){
  float u = 1.5957691216f * (x + 0.044715f*x*x*x);
  float t = 1.f - 2.f/(__expf(u) + 1.f);
  return 0.5f*x*(1.f + t);
}
// XCD-aware swizzle (verified R7: mdw_ln FETCH 164->38 MB)
__device__ __forceinline__ int swz8(int bid, int nblk){
  return (bid & 7) * (nblk >> 3) + (bid >> 3);
}

// ---------------- weight pre-convert: f32 [K][N] -> bf16 W^T [N][K] ----------------
__global__ __launch_bounds__(256) void convert_weights(
    const float* __restrict__ w0, const float* __restrict__ w1,
    const float* __restrict__ w2, const float* __restrict__ w3,
    const float* __restrict__ w4, const float* __restrict__ w5,
    short* __restrict__ dst){
  int t = blockIdx.x*256 + threadIdx.x;
  int e = t*4;
  if (e >= 479232) return;
  const float* src; int K, N, off;
  if      (e <  36864){ src=w0; K=192; N=192; off=0; }
  else if (e <  73728){ src=w1; K=192; N=192; off=36864; }
  else if (e < 147456){ src=w2; K=192; N=384; off=73728; }
  else if (e < 184320){ src=w3; K=192; N=192; off=147456; }
  else if (e < 331776){ src=w4; K=192; N=768; off=184320; }
  else                { src=w5; K=768; N=192; off=331776; }
  int le = e - off;
  int n = le / K, k = le % K;
  short4v o;
  #pragma unroll
  for (int l = 0; l < 4; ++l) o[l] = f2s(src[(size_t)(k+l)*N + n]);
  *(short4v*)(dst + e) = o;
}

// ---------------- fused cpe dwconv + residual + LN192 ----------------
// 1 wave = 1 position. Lane holds 3 ch (c = lane*3). Outputs:
//   x1out(f32) = in + conv + bias ; xnout(bf16) = LN(x1out)*g + b
__global__ __launch_bounds__(256) void cpe_ln_kernel(const float* __restrict__ in,
    const float* __restrict__ w, const float* __restrict__ bias,
    const float* __restrict__ g, const float* __restrict__ bb,
    float* __restrict__ x1out, bf16* __restrict__ xnout){
  int wv = threadIdx.x >> 6, lane = threadIdx.x & 63;
  int pos = swz8(blockIdx.x, gridDim.x)*4 + wv;
  int b = pos / NPOS; int ij = pos % NPOS; int i = ij / WW; int j = ij % WW;
  int c = lane * 3;
  float a0 = bias[c], a1 = bias[c+1], a2 = bias[c+2];
  #pragma unroll
  for (int di = 0; di < 3; ++di){
    int ii = i + di - 1;
    if (ii < 0 || ii >= HH) continue;
    #pragma unroll
    for (int dj = 0; dj < 3; ++dj){
      int jj = j + dj - 1;
      if (jj < 0 || jj >= WW) continue;
      const float* ip = in + ((size_t)b*NPOS + ii*WW + jj)*CC0 + c;
      const float* wp = w + (di*3 + dj)*CC0 + c;
      a0 += ip[0]*wp[0]; a1 += ip[1]*wp[1]; a2 += ip[2]*wp[2];
    }
  }
  size_t base = (size_t)pos*CC0 + c;
  const float* cp = in + base;
  float v0 = cp[0] + a0, v1 = cp[1] + a1, v2 = cp[2] + a2;
  float* xp = x1out + base;
  xp[0] = v0; xp[1] = v1; xp[2] = v2;
  float s = v0+v1+v2, q = v0*v0+v1*v1+v2*v2;
  #pragma unroll
  for (int m = 1; m < 64; m <<= 1){ s += __shfl_xor(s, m, 64); q += __shfl_xor(q, m, 64); }
  float mean = s * (1.f/CC0);
  float rstd = rsqrtf(q * (1.f/CC0) - mean*mean + 1e-5f);
  bf16* op = xnout + base;
  op[0] = f2b((v0-mean)*rstd*g[c]   + bb[c]);
  op[1] = f2b((v1-mean)*rstd*g[c+1] + bb[c+1]);
  op[2] = f2b((v2-mean)*rstd*g[c+2] + bb[c+2]);
}

// ---------------- vectorized depthwise 3x3 conv (XCD-swizzled) ----------------
// MODE 1: out(bf16) = silu(conv+bias)        (dwc, in bf16)
// MODE 2: out(bf16) += conv+bias             (lepe, in bf16, bf16 RMW)
template<typename TIN, int CC, int MODE>
__global__ __launch_bounds__(256) void dwconv_v(const TIN* __restrict__ in,
    const float* __restrict__ w, const float* __restrict__ bias, void* __restrict__ out){
  constexpr int VEC = 16 / (int)sizeof(TIN);
  constexpr int NG = CC / VEC;
  int idx = swz8(blockIdx.x, gridDim.x)*256 + threadIdx.x;
  int cg = idx % NG; int pos = idx / NG;
  int b = pos / NPOS; int ij = pos % NPOS; int i = ij / WW; int j = ij % WW;
  int cb = cg * VEC;
  float acc[VEC];
  #pragma unroll
  for (int l = 0; l < VEC; ++l) acc[l] = bias[cb + l];
  #pragma unroll
  for (int di = 0; di < 3; ++di){
    int ii = i + di - 1;
    if (ii < 0 || ii >= HH) continue;
    #pragma unroll
    for (int dj = 0; dj < 3; ++dj){
      int jj = j + dj - 1;
      if (jj < 0 || jj >= WW) continue;
      size_t off = ((size_t)b*NPOS + ii*WW + jj)*CC + cb;
      const float* wp = w + (di*3 + dj)*CC + cb;
      short8 v = *(const short8*)((const short*)in + off);
      #pragma unroll
      for (int l = 0; l < 8; ++l) acc[l] += s2f(v[l]) * wp[l];
    }
  }
  size_t oidx = (size_t)pos*CC + cb;
  if constexpr (MODE == 1){
    short8 o;
    #pragma unroll
    for (int l = 0; l < 8; ++l){ float s = acc[l]/(1.f + expf(-acc[l])); o[l] = f2s(s); }
    *(short8*)((short*)out + oidx) = o;
  } else {
    short* op = (short*)out + oidx;
    short8 r = *(short8*)op;
    short8 o;
    #pragma unroll
    for (int l = 0; l < 8; ++l) o[l] = f2s(s2f(r[l]) + acc[l]);
    *(short8*)op = o;
  }
}

// ---------------- MFMA GEMM: A [M,K] bf16-ish @ W^T [N,K] bf16 + bias ----------------
// ALOAD: 0 = bf16 direct, 1 = bf16 * bf16 product
// EPI: 0 = bf16, 1 = silu->bf16, 2 = elu+1 split ->bf16, 3 = +addf(f32) ->f32
#define BM 256
#define BN 64
#define BK 32
#define LDA 40
template<int K, int N, int ALOAD, int EPI>
__global__ __launch_bounds__(256) void mfma_gemm(
    const void* __restrict__ a0v, const void* __restrict__ a1v,
    const short* __restrict__ wT, const float* __restrict__ bias,
    const float* __restrict__ addf, void* __restrict__ out0, void* __restrict__ out1){
  __shared__ short As[BM*LDA];
  __shared__ short Bs[BN*LDA];
  int tid = threadIdx.x;
  int wave = tid >> 6, lane = tid & 63;
  size_t m0 = (size_t)blockIdx.x * BM;
  int n0 = blockIdx.y * BN;
  int wm = wave * 64;
  int am = lane & 15, ak = (lane >> 4) * 8;

  f32x4 acc[4][4];
  #pragma unroll
  for (int mt = 0; mt < 4; ++mt)
    #pragma unroll
    for (int nt = 0; nt < 4; ++nt)
      acc[mt][nt] = (f32x4){0.f,0.f,0.f,0.f};

  for (int k0 = 0; k0 < K; k0 += BK){
    if constexpr (ALOAD == 0){
      const short* A = (const short*)a0v;
      #pragma unroll
      for (int it = 0; it < 4; ++it){
        int idx = it*256 + tid;
        int row = idx >> 2; int ko = (idx & 3) * 8;
        short8 v = *(const short8*)(A + (m0 + row)*(size_t)K + k0 + ko);
        *(short8*)&As[row*LDA + ko] = v;
      }
    } else {
      const short* A0p = (const short*)a0v;
      const short* A1p = (const short*)a1v;
      #pragma unroll
      for (int it = 0; it < 4; ++it){
        int idx = it*256 + tid;
        int row = idx >> 2; int ko = (idx & 3) * 8;
        size_t off = (m0 + row)*(size_t)K + k0 + ko;
        short8 va = *(const short8*)(A0p + off);
        short8 vb = *(const short8*)(A1p + off);
        short8 o;
        #pragma unroll
        for (int l = 0; l < 8; ++l) o[l] = f2s(s2f(va[l]) * s2f(vb[l]));
        *(short8*)&As[row*LDA + ko] = o;
      }
    }
    {
      int row = tid >> 2; int ko = (tid & 3) * 8;
      short8 v = *(const short8*)(wT + (size_t)(n0 + row)*K + k0 + ko);
      *(short8*)&Bs[row*LDA + ko] = v;
    }
    __syncthreads();
    short8 af[4], bfr[4];
    #pragma unroll
    for (int mt = 0; mt < 4; ++mt) af[mt] = *(short8*)&As[(wm + mt*16 + am)*LDA + ak];
    #pragma unroll
    for (int nt = 0; nt < 4; ++nt) bfr[nt] = *(short8*)&Bs[(nt*16 + am)*LDA + ak];
    #pragma unroll
    for (int mt = 0; mt < 4; ++mt)
      #pragma unroll
      for (int nt = 0; nt < 4; ++nt)
        acc[mt][nt] = __builtin_amdgcn_mfma_f32_16x16x32_bf16(af[mt], bfr[nt], acc[mt][nt], 0, 0, 0);
    __syncthreads();
  }

  int cn = lane & 15;
  int cr = (lane >> 4) * 4;
  #pragma unroll
  for (int mt = 0; mt < 4; ++mt){
    #pragma unroll
    for (int nt = 0; nt < 4; ++nt){
      int gn = n0 + nt*16 + cn;
      float bv = bias[gn];
      #pragma unroll
      for (int r = 0; r < 4; ++r){
        size_t gm = m0 + wm + mt*16 + cr + r;
        float v = acc[mt][nt][r] + bv;
        if constexpr (EPI == 0){
          ((bf16*)out0)[gm*N + gn] = f2b(v);
        } else if constexpr (EPI == 1){
          ((bf16*)out0)[gm*N + gn] = f2b(v / (1.f + expf(-v)));
        } else if constexpr (EPI == 2){
          float rv = (v > 0.f) ? (v + 1.f) : expf(v);
          if (n0 < CC0) ((bf16*)out0)[gm*CC0 + gn] = f2b(rv);
          else          ((bf16*)out1)[gm*CC0 + (gn - CC0)] = f2b(rv);
        } else {
          ((float*)out0)[gm*N + gn] = addf[gm*N + gn] + v;
        }
      }
    }
  }
}

// ---------------- RoPE tables (H,W,96) ----------------
__global__ void rope_tables_kernel(float* __restrict__ cosT, float* __restrict__ sinT){
  int idx = blockIdx.x*256 + threadIdx.x;
  if (idx >= NPOS*96) return;
  int t = idx % 96; int ij = idx / 96; int i = ij / WW; int j = ij % WW;
  int kk = (t < 48) ? t : (t - 48);
  float th = expf(-(float)kk * 0.19188209108283716f);
  float pos = (t < 48) ? (float)i : (float)j;
  float ang = pos * th;
  cosT[idx] = cosf(ang);
  sinT[idx] = sinf(ang);
}

// ---------------- kmean (k in bf16) ----------------
__global__ __launch_bounds__(CC0) void kmean_kernel(const bf16* __restrict__ k, float* __restrict__ kmean){
  int b = blockIdx.x / 7; int chunk = blockIdx.x % 7; int c = threadIdx.x;
  const bf16* kp = k + ((size_t)b*NPOS + (size_t)chunk*448)*CC0 + c;
  float s = 0.f;
  for (int r = 0; r < 448; ++r) s += b2f(kp[(size_t)r*CC0]);
  atomicAdd(&kmean[b*CC0 + c], s * (1.f/NPOS));
}

// ---------------- kv (k, h in bf16), 14 N-chunks (R7: 56 chunks regressed - atomics) ----------------
#define KVCH 14
__global__ __launch_bounds__(256) void kv_kernel(const bf16* __restrict__ kbuf,
    const bf16* __restrict__ hbuf, const float* __restrict__ cosT,
    const float* __restrict__ sinT, float* __restrict__ kv){
  int bi = blockIdx.x;
  int chunk = bi % KVCH; bi /= KVCH;
  int h = bi % NHH; int b = bi / NHH;
  int tid = threadIdx.x;
  int r8 = tid >> 5, lane = tid & 31;
  __shared__ float krs[8][32];
  __shared__ float vvs[8][32];
  int d = tid >> 3; int ebase = (tid & 7) * 4;
  float a0 = 0.f, a1 = 0.f, a2 = 0.f, a3 = 0.f;
  int c = h*HDD + lane;
  int t = c >> 1;
  bool odd = (lane & 1);
  for (int step = 0; step < NPOS/(KVCH*8); ++step){
    int n = chunk*(NPOS/KVCH) + step*8 + r8;
    size_t row = (size_t)b*NPOS + n;
    float kc = b2f(kbuf[row*CC0 + c]);
    float kp = b2f(kbuf[row*CC0 + (c ^ 1)]);
    float cs = cosT[(size_t)n*96 + t], sn = sinT[(size_t)n*96 + t];
    krs[r8][lane] = odd ? (cs*kc + sn*kp) : (cs*kc - sn*kp);
    vvs[r8][lane] = b2f(hbuf[row*CC0 + c]);
    __syncthreads();
    #pragma unroll
    for (int nn = 0; nn < 8; ++nn){
      float kk2 = krs[nn][d];
      a0 += kk2 * vvs[nn][ebase+0];
      a1 += kk2 * vvs[nn][ebase+1];
      a2 += kk2 * vvs[nn][ebase+2];
      a3 += kk2 * vvs[nn][ebase+3];
    }
    __syncthreads();
  }
  const float invN = 1.f/NPOS;
  float* kvp = kv + (((size_t)(b*NHH + h)*HDD + d)*HDD) + ebase;
  atomicAdd(kvp+0, a0*invN);
  atomicAdd(kvp+1, a1*invN);
  atomicAdd(kvp+2, a2*invN);
  atomicAdd(kvp+3, a3*invN);
}

// ---------------- fused attention (q bf16 in, attn bf16 out) ----------------
__global__ __launch_bounds__(CC0) void attn_kernel(const bf16* __restrict__ q,
    const float* __restrict__ kmean, const float* __restrict__ kv,
    const float* __restrict__ cosT, const float* __restrict__ sinT,
    bf16* __restrict__ out){
  int row = blockIdx.x;
  int tid = threadIdx.x;
  int b = row / NPOS; int n = row % NPOS;
  __shared__ float qs[CC0];
  __shared__ float qrs[NHH*33];
  __shared__ float zsh[NHH];
  qs[tid] = b2f(q[(size_t)row*CC0 + tid]);
  __syncthreads();
  float pm = qs[tid] * kmean[b*CC0 + tid];
  #pragma unroll
  for (int m = 16; m >= 1; m >>= 1) pm += __shfl_xor(pm, m, 32);
  if ((tid & 31) == 0) zsh[tid >> 5] = 1.f/(pm + 1e-6f);
  int t = tid >> 1;
  float cs = cosT[(size_t)n*96 + t], sn = sinT[(size_t)n*96 + t];
  float qr = (tid & 1) ? (cs*qs[tid] + sn*qs[tid-1]) : (cs*qs[tid] - sn*qs[tid+1]);
  int hh = tid >> 5, d = tid & 31;
  qrs[hh*33 + d] = qr;
  __syncthreads();
  const float* kvp = kv + (size_t)(b*NHH + hh)*HDD*HDD;
  float acc = 0.f;
  #pragma unroll
  for (int d2 = 0; d2 < HDD; ++d2) acc += qrs[hh*33 + d2] * kvp[d2*HDD + d];
  out[(size_t)row*CC0 + tid] = f2b(acc * zsh[hh]);
}

// ---------------- fused mdw dwconv + n1/n2/n3 LN chain + gelu (XCD-swizzled) ----------------
__global__ __launch_bounds__(256) void mdw_ln_kernel(const bf16* __restrict__ f1,
    const float* __restrict__ w, const float* __restrict__ bias,
    const float* __restrict__ g1, const float* __restrict__ b1,
    const float* __restrict__ g2, const float* __restrict__ b2,
    const float* __restrict__ g3, const float* __restrict__ b3,
    bf16* __restrict__ out){
  int wv = threadIdx.x >> 6, lane = threadIdx.x & 63;
  int pos = swz8(blockIdx.x, gridDim.x)*4 + wv;
  int b = pos / NPOS; int ij = pos % NPOS; int i = ij / WW; int j = ij % WW;
  size_t rowbase = (size_t)pos * C4;
  int c0 = lane * 8;
  int c1 = 512 + lane * 4;

  float v[12], f[12];
  {
    f32x4 bv0 = *(const f32x4*)(bias + c0);
    f32x4 bv1 = *(const f32x4*)(bias + c0 + 4);
    f32x4 bv2 = *(const f32x4*)(bias + c1);
    #pragma unroll
    for (int l = 0; l < 4; ++l){ v[l] = bv0[l]; v[4+l] = bv1[l]; v[8+l] = bv2[l]; }
  }
  #pragma unroll
  for (int di = 0; di < 3; ++di){
    int ii = i + di - 1;
    if (ii < 0 || ii >= HH) continue;
    #pragma unroll
    for (int dj = 0; dj < 3; ++dj){
      int jj = j + dj - 1;
      if (jj < 0 || jj >= WW) continue;
      size_t off = ((size_t)b*NPOS + ii*WW + jj)*C4;
      const float* wp = w + (di*3 + dj)*C4;
      short8 x0 = *(const short8*)((const short*)f1 + off + c0);
      short4v x1 = *(const short4v*)((const short*)f1 + off + c1);
      f32x4 w0 = *(const f32x4*)(wp + c0);
      f32x4 w1 = *(const f32x4*)(wp + c0 + 4);
      f32x4 w2 = *(const f32x4*)(wp + c1);
      #pragma unroll
      for (int l = 0; l < 4; ++l){
        v[l]   += s2f(x0[l])   * w0[l];
        v[4+l] += s2f(x0[4+l]) * w1[l];
        v[8+l] += s2f(x1[l])   * w2[l];
      }
    }
  }
  {
    short8 x0 = *(const short8*)((const short*)f1 + rowbase + c0);
    short4v x1 = *(const short4v*)((const short*)f1 + rowbase + c1);
    #pragma unroll
    for (int l = 0; l < 8; ++l){ f[l] = s2f(x0[l]); v[l] += f[l]; }
    #pragma unroll
    for (int l = 0; l < 4; ++l){ f[8+l] = s2f(x1[l]); v[8+l] += f[8+l]; }
  }
  const float* gs[3] = {g1, g2, g3};
  const float* bs[3] = {b1, b2, b3};
  #pragma unroll
  for (int pass = 0; pass < 3; ++pass){
    float s = 0.f, q = 0.f;
    #pragma unroll
    for (int l = 0; l < 12; ++l){ s += v[l]; q += v[l]*v[l]; }
    #pragma unroll
    for (int m = 1; m < 64; m <<= 1){ s += __shfl_xor(s, m, 64); q += __shfl_xor(q, m, 64); }
    float mean = s * (1.f/C4);
    float rstd = rsqrtf(q * (1.f/C4) - mean*mean + 1e-5f);
    f32x4 g0 = *(const f32x4*)(gs[pass] + c0);
    f32x4 g1v = *(const f32x4*)(gs[pass] + c0 + 4);
    f32x4 g2v = *(const f32x4*)(gs[pass] + c1);
    f32x4 bb0 = *(const f32x4*)(bs[pass] + c0);
    f32x4 bb1 = *(const f32x4*)(bs[pass] + c0 + 4);
    f32x4 bb2 = *(const f32x4*)(bs[pass] + c1);
    #pragma unroll
    for (int l = 0; l < 4; ++l){
      v[l]   = (v[l]  -mean)*rstd*g0[l]  + bb0[l];
      v[4+l] = (v[4+l]-mean)*rstd*g1v[l] + bb1[l];
      v[8+l] = (v[8+l]-mean)*rstd*g2v[l] + bb2[l];
    }
    if (pass < 2){
      #pragma unroll
      for (int l = 0; l < 12; ++l) v[l] += f[l];
    }
  }
  short8 o0; short4v o1;
  #pragma unroll
  for (int l = 0; l < 8; ++l) o0[l] = f2s(fast_gelu(v[l]));
  #pragma unroll
  for (int l = 0; l < 4; ++l) o1[l] = f2s(fast_gelu(v[8+l]));
  *(short8*)((short*)out + rowbase + c0) = o0;
  *(short4v*)((short*)out + rowbase + c1) = o1;
}

extern "C" void kernel_launch(void* const* d_in, const int* in_sizes, int n_in,
                              void* d_out, int out_size, void* d_ws, size_t ws_size,
                              hipStream_t stream){
  (void)in_sizes; (void)n_in; (void)out_size; (void)ws_size;
  const float* X      = (const float*)d_in[0];
  const float* cpe1_w = (const float*)d_in[1];
  const float* cpe1_b = (const float*)d_in[2];
  const float* n1g    = (const float*)d_in[3];
  const float* n1b    = (const float*)d_in[4];
  const float* in_w   = (const float*)d_in[5];
  const float* in_b   = (const float*)d_in[6];
  const float* actp_w = (const float*)d_in[7];
  const float* actp_b = (const float*)d_in[8];
  const float* dwc_w  = (const float*)d_in[9];
  const float* dwc_b  = (const float*)d_in[10];
  const float* qk_w   = (const float*)d_in[11];
  const float* qk_b   = (const float*)d_in[12];
  const float* lepe_w = (const float*)d_in[13];
  const float* lepe_b = (const float*)d_in[14];
  const float* outp_w = (const float*)d_in[15];
  const float* outp_b = (const float*)d_in[16];
  const float* cpe2_w = (const float*)d_in[17];
  const float* cpe2_b = (const float*)d_in[18];
  const float* n2g    = (const float*)d_in[19];
  const float* n2b    = (const float*)d_in[20];
  const float* fc1_w  = (const float*)d_in[21];
  const float* fc1_b  = (const float*)d_in[22];
  const float* mdw_w  = (const float*)d_in[23];
  const float* mdw_b  = (const float*)d_in[24];
  const float* fc2_w  = (const float*)d_in[25];
  const float* fc2_b  = (const float*)d_in[26];
  const float* mn1g   = (const float*)d_in[27];
  const float* mn1b   = (const float*)d_in[28];
  const float* mn2g   = (const float*)d_in[29];
  const float* mn2b   = (const float*)d_in[30];
  const float* mn3g   = (const float*)d_in[31];
  const float* mn3b   = (const float*)d_in[32];

  char* ws = (char*)d_ws;
  const size_t SZF = (size_t)MROWS*CC0*4;
  const size_t SZB = (size_t)MROWS*CC0*2;
  float* A0 = (float*)(ws);                 // x1 -> x3 (f32 residual spine)
  char* base2 = ws + SZF;
  bf16* BQ = (bf16*)(base2 + 0*SZB);        // q
  bf16* BKb= (bf16*)(base2 + 1*SZB);        // k
  bf16* BA = (bf16*)(base2 + 2*SZB);        // attn (+lepe)
  bf16* B1 = (bf16*)(base2 + 3*SZB);        // act_res
  bf16* B0 = (bf16*)(base2 + 4*SZB);        // xn -> xm
  bf16* B2 = (bf16*)(base2 + 5*SZB);        // t
  bf16* B3 = (bf16*)(base2 + 6*SZB);        // h
  float* A1 = (float*)(base2);              // x2 (f32) overlays BQ+BK
  bf16*  F1 = (bf16*)(base2);               // f1 overlays slots 0-3
  bf16*  DW = (bf16*)(base2 + 4*SZB);       // gelu(n3) overlays slots 4-7
  short* WT = (short*)(base2 + 8*SZB);
  char* tail = (char*)(WT + 479232 + 64);
  float* KMEAN = (float*)tail;                 tail += (size_t)BB*CC0*4;
  float* KV    = (float*)tail;                 tail += (size_t)BB*NHH*HDD*HDD*4;
  float* COS   = (float*)tail;                 tail += (size_t)NPOS*96*4;
  float* SIN   = (float*)tail;

  const short* actpT = WT + 0;
  const short* inT   = WT + 36864;
  const short* qkT   = WT + 73728;
  const short* outpT = WT + 147456;
  const short* fc1T  = WT + 184320;
  const short* fc2T  = WT + 331776;

  const int G192B = (MROWS*(CC0/8))/256;   // 4704 (8 | G)
  const int GPOS4 = MROWS/4;               // 12544 (8 | G)

  convert_weights<<<(479232/4 + 255)/256, 256, 0, stream>>>(actp_w, in_w, qk_w, outp_w, fc1_w, fc2_w, WT);
  rope_tables_kernel<<<(NPOS*96 + 255)/256, 256, 0, stream>>>(COS, SIN);
  // 1+2. x1 = x + cpe1(x); xn = LN(x1)  (fused)
  cpe_ln_kernel<<<GPOS4, 256, 0, stream>>>(X, cpe1_w, cpe1_b, n1g, n1b, A0, B0);
  // 3. act_res = silu(xn@actp)
  mfma_gemm<CC0,CC0,0,1><<<dim3(MROWS/BM,CC0/BN), 256, 0, stream>>>(B0, nullptr, actpT, actp_b, nullptr, B1, nullptr);
  // 4. t = xn@in_w + b
  mfma_gemm<CC0,CC0,0,0><<<dim3(MROWS/BM,CC0/BN), 256, 0, stream>>>(B0, nullptr, inT, in_b, nullptr, B2, nullptr);
  // 5. h = silu(dwc(t))
  dwconv_v<bf16,CC0,1><<<G192B, 256, 0, stream>>>(B2, dwc_w, dwc_b, B3);
  // 6. qk = h@qk_w; q->BQ, k->BK (bf16, elu+1)
  mfma_gemm<CC0,2*CC0,0,2><<<dim3(MROWS/BM,2*CC0/BN), 256, 0, stream>>>(B3, nullptr, qkT, qk_b, nullptr, BQ, BKb);
  // 7. kmean, kv
  hipMemsetAsync(KMEAN, 0, (size_t)BB*CC0*4, stream);
  hipMemsetAsync(KV, 0, (size_t)BB*NHH*HDD*HDD*4, stream);
  kmean_kernel<<<BB*7, CC0, 0, stream>>>(BKb, KMEAN);
  kv_kernel<<<BB*NHH*KVCH, 256, 0, stream>>>(BKb, B3, COS, SIN, KV);
  // 8. attn core -> BA
  attn_kernel<<<MROWS, CC0, 0, stream>>>(BQ, KMEAN, KV, COS, SIN, BA);
  // 9. attn += lepe(h)
  dwconv_v<bf16,CC0,2><<<G192B, 256, 0, stream>>>(B3, lepe_w, lepe_b, BA);
  // 10. x2 = x1 + (attn*act_res)@outp + b -> A1
  mfma_gemm<CC0,CC0,1,3><<<dim3(MROWS/BM,CC0/BN), 256, 0, stream>>>(BA, B1, outpT, outp_b, A0, A1, nullptr);
  // 11+12. x3 = x2 + cpe2(x2) -> A0 ; xm = LN(x3) -> B0  (fused)
  cpe_ln_kernel<<<GPOS4, 256, 0, stream>>>(A1, cpe2_w, cpe2_b, n2g, n2b, A0, B0);
  // 13. f1 = xm@fc1 + b -> F1
  mfma_gemm<CC0,C4,0,0><<<dim3(MROWS/BM,C4/BN), 256, 0, stream>>>(B0, nullptr, fc1T, fc1_b, nullptr, F1, nullptr);
  // 14. fused: mdw conv + n1..n3 LN chain + gelu -> DW
  mdw_ln_kernel<<<GPOS4, 256, 0, stream>>>(F1, mdw_w, mdw_b, mn1g, mn1b, mn2g, mn2b, mn3g, mn3b, DW);
  // 15. out = x3 + gelu(n3)@fc2 + b (f32)
  mfma_gemm<C4,CC0,0,3><<<dim3(MROWS/BM,CC0/BN), 256, 0, stream>>>(DW, nullptr, fc2T, fc2_b, A0, d_out, nullptr);
}